// Round 15
// baseline (171.966 us; speedup 1.0000x reference)
//
#include <hip/hip_runtime.h>
#include <hip/hip_bf16.h>
#include <stdint.h>

#define NUM_IN  2048   // K
#define NUM_OUT 8192   // N
#define BATCH   4096   // M
#define SD      5

#define BM 256
#define BN 256
#define BK 64
#define NT (NUM_IN / BK)      // 32 K-tiles
#define TILEE (BM * BK)       // 16384 elements per operand per K-tile

typedef __bf16 bf16x8 __attribute__((ext_vector_type(8)));
typedef float  f32x16 __attribute__((ext_vector_type(16)));
typedef unsigned short ushort_t;
typedef ushort_t ushort8 __attribute__((ext_vector_type(8)));

static __device__ __forceinline__ ushort_t bf16_bits(float f) {
  __hip_bfloat16 h = __float2bfloat16(f);
  ushort_t u;
  __builtin_memcpy(&u, &h, 2);
  return u;
}

// ---------- fused aux: blocks [0,512) genw, [512,1024) cvt ----------
__global__ __launch_bounds__(256) void aux_kernel(
    const float* __restrict__ inputs,   // [BATCH][NUM_IN] f32
    ushort_t* __restrict__ Abf,         // [BATCH][NUM_IN] bf16
    const float* __restrict__ in_pos, const float* __restrict__ out_pos,
    const float* __restrict__ init_in, const float* __restrict__ init_out,
    ushort_t* __restrict__ Wt) {        // [NUM_OUT][NUM_IN] bf16
  __shared__ float s_ip[NUM_IN * SD];    // 40 KB
  __shared__ float s_iip[NUM_IN * SD];   // 40 KB
  const int tid = threadIdx.x;

  if (blockIdx.x >= 512) {
    // ---- cvt path ----
    const size_t base = (size_t)(blockIdx.x - 512) * 16384;
#pragma unroll
    for (int c = 0; c < 8; ++c) {
      const size_t i = base + (size_t)c * 2048 + tid * 8;
      float4 v0 = *reinterpret_cast<const float4*>(inputs + i);
      float4 v1 = *reinterpret_cast<const float4*>(inputs + i + 4);
      ushort8 o;
      o[0] = bf16_bits(v0.x); o[1] = bf16_bits(v0.y);
      o[2] = bf16_bits(v0.z); o[3] = bf16_bits(v0.w);
      o[4] = bf16_bits(v1.x); o[5] = bf16_bits(v1.y);
      o[6] = bf16_bits(v1.z); o[7] = bf16_bits(v1.w);
      *reinterpret_cast<ushort8*>(Abf + i) = o;
    }
    return;
  }

  // ---- genw path ----
#pragma unroll
  for (int i = 0; i < 10; ++i) {
    const int idx = i * 1024 + tid * 4;
    *reinterpret_cast<float4*>(&s_ip[idx]) =
        *reinterpret_cast<const float4*>(in_pos + idx);
    *reinterpret_cast<float4*>(&s_iip[idx]) =
        *reinterpret_cast<const float4*>(init_in + idx);
  }
  __syncthreads();

  const int n  = blockIdx.x * 16 + (tid >> 4);
  const int kg = tid & 15;
  float op[SD], iop[SD];
#pragma unroll
  for (int d = 0; d < SD; ++d) {
    op[d]  = out_pos[n * SD + d];
    iop[d] = init_out[n * SD + d];
  }
#pragma unroll 1
  for (int kb = 0; kb < 16; ++kb) {
    const int k0 = kb * 128 + kg * 8;
    float buf[40], ibuf[40];
#pragma unroll
    for (int j = 0; j < 10; ++j) {
      float4 v = *reinterpret_cast<const float4*>(&s_ip[k0 * SD + j * 4]);
      buf[4 * j + 0] = v.x; buf[4 * j + 1] = v.y;
      buf[4 * j + 2] = v.z; buf[4 * j + 3] = v.w;
      float4 u = *reinterpret_cast<const float4*>(&s_iip[k0 * SD + j * 4]);
      ibuf[4 * j + 0] = u.x; ibuf[4 * j + 1] = u.y;
      ibuf[4 * j + 2] = u.z; ibuf[4 * j + 3] = u.w;
    }
    ushort8 o;
#pragma unroll
    for (int i = 0; i < 8; ++i) {
      float d1 = 0.f, d0 = 0.f;
#pragma unroll
      for (int d = 0; d < SD; ++d) {
        float a = buf[i * SD + d] - op[d];
        float b = ibuf[i * SD + d] - iop[d];
        d1 += a * a;
        d0 += b * b;
      }
      o[i] = bf16_bits(sqrtf(d1) - sqrtf(d0));
    }
    *reinterpret_cast<ushort8*>(Wt + (size_t)n * NUM_IN + k0) = o;
  }
}

// ---------- GEMM: r7 structure + mfma_f32_32x32x16_bf16 ----------
// Same staging/swizzle/barrier structure as the 128.6us r7 kernel (dbuf
// BK=64, 1 barrier + vmcnt(0)/K-tile, counted-lgkm lookahead). MFMA shape
// switched to 32x32x16 (2495 vs 2075 TF ceiling -> 17% less MFMA-pipe time,
// half the instructions). Wave tile 128x64 = 4 Mblk x 2 Nblk of 32x32.
// Frag reads at k-step s: row base+(l&31), chunk (2s+(l>>5))^(l&7) -> each
// 16B slot hit by exactly 8 lanes = b128 minimum (conflict-free, same
// uniformity class as the measured-zero 16x16 pattern).
// 32x32 A/B/D layouts validated in rounds 3/4 (absmax passed).
__global__ __launch_bounds__(512, 1) void gemm_kernel(
    const ushort_t* __restrict__ A,    // [M][K] bf16
    const ushort_t* __restrict__ Bt,   // [N][K] bf16
    const float* __restrict__ bias,    // [N]
    float* __restrict__ C) {           // [M][N] f32
  __shared__ __align__(16) ushort_t sA[2 * TILEE];   // 64 KiB
  __shared__ __align__(16) ushort_t sB[2 * TILEE];   // 64 KiB

  const int tid  = threadIdx.x;
  const int w    = tid >> 6;         // 0..7
  const int l    = tid & 63;
  const int wm   = w >> 2;           // 0..1
  const int wn   = w & 3;            // 0..3
  const int rl   = l & 31;
  const int hi   = l >> 5;           // 0..1
  const int swz  = l & 7;

  // bijective XCD swizzle (512 = 8*64)
  const int orig = blockIdx.x;
  const int lin  = (orig & 7) * 64 + (orig >> 3);
  const int bx   = lin >> 4;         // 0..31 N-block
  const int by   = lin & 15;         // 0..15 M-block
  const int m0   = by * BM;
  const int n0   = bx * BN;

  // fragment read k-chunk offsets per k-step s (elements)
  const int cks0 = ((0 + hi) ^ swz) * 8;
  const int cks1 = ((2 + hi) ^ swz) * 8;
  const int cks2 = ((4 + hi) ^ swz) * 8;
  const int cks3 = ((6 + hi) ^ swz) * 8;
  // A row base (within half, elements): half (mb>>1), row wm*64+(mb&1)*32+rl
  const int AbW = (wm * 64 + rl) * 64;   // + (mb>>1)*8192 + (mb&1)*2048
  // B: half nb, row wn*32 + rl
  const int BbW = (wn * 32 + rl) * 64;   // + nb*8192

  // staging geometry (identical to r7; verified zero-conflict)
  const int d0 = tid, d1 = tid + 512;
  const int lr0 = d0 >> 3, lr1 = d1 >> 3;
  const int c0 = (d0 & 7) ^ (lr0 & 7);
  const int c1 = (d1 & 7) ^ (lr1 & 7);
  const ushort_t* pA0 = A  + (size_t)(m0 + (lr0 >> 6) * 128 + (lr0 & 63)) * NUM_IN + c0 * 8;
  const ushort_t* pA1 = A  + (size_t)(m0 + (lr1 >> 6) * 128 + (lr1 & 63)) * NUM_IN + c1 * 8;
  const ushort_t* pB0 = Bt + (size_t)(n0 + (lr0 >> 5) * 64 + (lr0 & 31)) * NUM_IN + c0 * 8;
  const ushort_t* pB1 = Bt + (size_t)(n0 + (lr1 >> 5) * 64 + (lr1 & 31)) * NUM_IN + c1 * 8;

#define GLDS(src, dst)                                                         \
  __builtin_amdgcn_global_load_lds(                                            \
      reinterpret_cast<const __attribute__((address_space(1))) uint32_t*>(     \
          (uintptr_t)(src)),                                                   \
      reinterpret_cast<__attribute__((address_space(3))) uint32_t*>(           \
          (uintptr_t)(dst)),                                                   \
      16, 0, 0)

#define STAGE_A(bs, mh, kt)                                                    \
  {                                                                            \
    GLDS(pA0 + (size_t)(mh) * 64 * NUM_IN + (kt),                              \
         &sA[(bs) * TILEE + (mh) * 8192 + tid * 8]);                           \
    GLDS(pA1 + (size_t)(mh) * 64 * NUM_IN + (kt),                              \
         &sA[(bs) * TILEE + (mh) * 8192 + tid * 8 + 4096]);                    \
  }
#define STAGE_B(bs, nh, kt)                                                    \
  {                                                                            \
    GLDS(pB0 + (size_t)(nh) * 32 * NUM_IN + (kt),                              \
         &sB[(bs) * TILEE + (nh) * 8192 + tid * 8]);                           \
    GLDS(pB1 + (size_t)(nh) * 32 * NUM_IN + (kt),                              \
         &sB[(bs) * TILEE + (nh) * 8192 + tid * 8 + 4096]);                    \
  }

// 4 ds_read_b128: all 4 A M-blocks at k-step s (ck = per-lane constant)
#define RD_A32(arr, bs, ck)                                                    \
  {                                                                            \
    _Pragma("unroll")                                                          \
    for (int mb = 0; mb < 4; ++mb)                                             \
      arr[mb] = *reinterpret_cast<const bf16x8*>(                              \
          &sA[(bs) * TILEE + (mb >> 1) * 8192 + (mb & 1) * 2048 + AbW + (ck)]);\
  }
// 2 ds_read_b128: both B N-blocks at k-step s
#define RD_B32(arr, bs, ck)                                                    \
  {                                                                            \
    _Pragma("unroll")                                                          \
    for (int nb = 0; nb < 2; ++nb)                                             \
      arr[nb] = *reinterpret_cast<const bf16x8*>(                              \
          &sB[(bs) * TILEE + nb * 8192 + BbW + (ck)]);                         \
  }

// 8 MFMA 32x32x16: full wave tile, one k-step
#define MFMA8(Aa, Bx)                                                          \
  {                                                                            \
    __builtin_amdgcn_s_setprio(1);                                             \
    _Pragma("unroll")                                                          \
    for (int mb = 0; mb < 4; ++mb)                                             \
      _Pragma("unroll")                                                        \
      for (int nb = 0; nb < 2; ++nb)                                           \
        acc[mb][nb] = __builtin_amdgcn_mfma_f32_32x32x16_bf16(                 \
            Aa[mb], Bx[nb], acc[mb][nb], 0, 0, 0);                             \
    __builtin_amdgcn_s_setprio(0);                                             \
  }

#define LGKM(n)  asm volatile("s_waitcnt lgkmcnt(" #n ")" ::: "memory")
#define SCHED0   __builtin_amdgcn_sched_barrier(0)
#define BARRIER  __builtin_amdgcn_s_barrier()
#define VMCNT0   asm volatile("s_waitcnt vmcnt(0)" ::: "memory")

// One K-tile: 4 k-steps of 8 MFMA; one-step read lookahead; FIFO ledger:
// RD(s0)+RD(s1)=12 -> LGKM(6) s0 ready -> M(s0) -> RD(s2) -> LGKM(6) s1
// ready -> M(s1) -> RD(s3) -> LGKM(6) s2 ready -> M(s2) -> LGKM(0) -> M(s3).
// Register sets alternate (aX/aY, bX/bY); refills issued after last use.
#define KTILE(CUR, NXT, ktn)                                                   \
  {                                                                            \
    STAGE_A(NXT, 0, ktn)                                                       \
    RD_A32(aX, CUR, cks0) RD_B32(bX, CUR, cks0)                                \
    RD_A32(aY, CUR, cks1) RD_B32(bY, CUR, cks1)                                \
    LGKM(6); SCHED0;                                                           \
    MFMA8(aX, bX)                                                              \
    STAGE_B(NXT, 0, ktn)                                                       \
    RD_A32(aX, CUR, cks2) RD_B32(bX, CUR, cks2)                                \
    LGKM(6); SCHED0;                                                           \
    MFMA8(aY, bY)                                                              \
    STAGE_A(NXT, 1, ktn)                                                       \
    RD_A32(aY, CUR, cks3) RD_B32(bY, CUR, cks3)                                \
    LGKM(6); SCHED0;                                                           \
    MFMA8(aX, bX)                                                              \
    STAGE_B(NXT, 1, ktn)                                                       \
    LGKM(0); SCHED0;                                                           \
    MFMA8(aY, bY)                                                              \
    VMCNT0;                                                                    \
    BARRIER;                                                                   \
  }

  f32x16 acc[4][2];
#pragma unroll
  for (int i = 0; i < 4; ++i)
#pragma unroll
    for (int j = 0; j < 2; ++j)
#pragma unroll
      for (int r = 0; r < 16; ++r) acc[i][j][r] = 0.f;

  bf16x8 aX[4], aY[4], bX[2], bY[2];

  // prologue: stage tile 0 into buf0
  STAGE_A(0, 0, 0) STAGE_B(0, 0, 0) STAGE_A(0, 1, 0) STAGE_B(0, 1, 0)
  VMCNT0;
  BARRIER;

#pragma unroll 1
  for (int tt = 0; tt < NT; tt += 2) {
    const int k1 = (tt + 1) * BK;                          // always < NUM_IN
    const int k2 = (tt + 2 < NT ? tt + 2 : NT - 1) * BK;   // clamped tail
    KTILE(0, 1, k1)
    KTILE(1, 0, k2)
  }

  // ---- epilogue: C = acc + bias ----
  // D layout (32x32): col = l&31, row = (reg&3) + 8*(reg>>2) + 4*(l>>5)
  const int crow = m0 + wm * 128 + 4 * hi;
  const int ccol = n0 + wn * 64 + rl;
#pragma unroll
  for (int nb = 0; nb < 2; ++nb) {
    const float bi = bias[ccol + nb * 32];
#pragma unroll
    for (int mb = 0; mb < 4; ++mb) {
#pragma unroll
      for (int reg = 0; reg < 16; ++reg) {
        const int r = crow + mb * 32 + (reg & 3) + 8 * (reg >> 2);
        C[(size_t)r * NUM_OUT + ccol + nb * 32] = acc[mb][nb][reg] + bi;
      }
    }
  }
#undef KTILE
#undef STAGE_A
#undef STAGE_B
#undef RD_A32
#undef RD_B32
#undef MFMA8
#undef GLDS
}

extern "C" void kernel_launch(void* const* d_in, const int* in_sizes, int n_in,
                              void* d_out, int out_size, void* d_ws, size_t ws_size,
                              hipStream_t stream) {
  const float* inputs   = (const float*)d_in[0];  // [4096,2048]
  const float* init_in  = (const float*)d_in[1];  // [2048,1,5]
  const float* init_out = (const float*)d_in[2];  // [1,8192,5]
  const float* in_pos   = (const float*)d_in[3];  // [2048,1,5]
  const float* out_pos  = (const float*)d_in[4];  // [1,8192,5]
  const float* biases   = (const float*)d_in[5];  // [8192]
  float* out = (float*)d_out;                     // [4096,8192]

  ushort_t* Abf = (ushort_t*)d_ws;
  ushort_t* Wt  = (ushort_t*)((char*)d_ws + (size_t)BATCH * NUM_IN * 2);

  aux_kernel<<<1024, 256, 0, stream>>>(inputs, Abf,
                                       in_pos, out_pos, init_in, init_out, Wt);
  gemm_kernel<<<(BATCH / BM) * (NUM_OUT / BN), 512, 0, stream>>>(
      Abf, Wt, biases, out);
}

// Round 16
// 159.983 us; speedup vs baseline: 1.0749x; 1.0749x over previous
//
#include <hip/hip_runtime.h>
#include <hip/hip_bf16.h>
#include <stdint.h>

#define NUM_IN  2048   // K
#define NUM_OUT 8192   // N
#define BATCH   4096   // M
#define SD      5

#define BM 256
#define BN 256
#define BK 64
#define NT (NUM_IN / BK)      // 32 K-tiles
#define TILEE (BM * BK)       // 16384 elements per operand per K-tile

typedef __bf16 bf16x8 __attribute__((ext_vector_type(8)));
typedef float  f32x4  __attribute__((ext_vector_type(4)));
typedef unsigned short ushort_t;
typedef ushort_t ushort8 __attribute__((ext_vector_type(8)));

static __device__ __forceinline__ ushort_t bf16_bits(float f) {
  __hip_bfloat16 h = __float2bfloat16(f);
  ushort_t u;
  __builtin_memcpy(&u, &h, 2);
  return u;
}

// ---------- fused aux: blocks [0,256) genw (32 n each), [256,512) cvt ----------
// genw stages the 80KB pos tables ONCE per 32 n (was: per 16 n) -> halves
// the cross-block staging redundancy. cvt: 32768 f32->bf16 per block.
__global__ __launch_bounds__(256) void aux_kernel(
    const float* __restrict__ inputs,   // [BATCH][NUM_IN] f32
    ushort_t* __restrict__ Abf,         // [BATCH][NUM_IN] bf16
    const float* __restrict__ in_pos, const float* __restrict__ out_pos,
    const float* __restrict__ init_in, const float* __restrict__ init_out,
    ushort_t* __restrict__ Wt) {        // [NUM_OUT][NUM_IN] bf16
  __shared__ float s_ip[NUM_IN * SD];    // 40 KB
  __shared__ float s_iip[NUM_IN * SD];   // 40 KB
  const int tid = threadIdx.x;

  if (blockIdx.x >= 256) {
    // ---- cvt path: 32768 elems ----
    const size_t base = (size_t)(blockIdx.x - 256) * 32768;
#pragma unroll
    for (int c = 0; c < 16; ++c) {
      const size_t i = base + (size_t)c * 2048 + tid * 8;
      float4 v0 = *reinterpret_cast<const float4*>(inputs + i);
      float4 v1 = *reinterpret_cast<const float4*>(inputs + i + 4);
      ushort8 o;
      o[0] = bf16_bits(v0.x); o[1] = bf16_bits(v0.y);
      o[2] = bf16_bits(v0.z); o[3] = bf16_bits(v0.w);
      o[4] = bf16_bits(v1.x); o[5] = bf16_bits(v1.y);
      o[6] = bf16_bits(v1.z); o[7] = bf16_bits(v1.w);
      *reinterpret_cast<ushort8*>(Abf + i) = o;
    }
    return;
  }

  // ---- genw path: 32 n per block ----
#pragma unroll
  for (int i = 0; i < 10; ++i) {
    const int idx = i * 1024 + tid * 4;
    *reinterpret_cast<float4*>(&s_ip[idx]) =
        *reinterpret_cast<const float4*>(in_pos + idx);
    *reinterpret_cast<float4*>(&s_iip[idx]) =
        *reinterpret_cast<const float4*>(init_in + idx);
  }
  __syncthreads();

#pragma unroll 1
  for (int half = 0; half < 2; ++half) {
    const int n  = blockIdx.x * 32 + half * 16 + (tid >> 4);
    const int kg = tid & 15;
    float op[SD], iop[SD];
#pragma unroll
    for (int d = 0; d < SD; ++d) {
      op[d]  = out_pos[n * SD + d];
      iop[d] = init_out[n * SD + d];
    }
#pragma unroll 1
    for (int kb = 0; kb < 16; ++kb) {
      const int k0 = kb * 128 + kg * 8;
      float buf[40], ibuf[40];
#pragma unroll
      for (int j = 0; j < 10; ++j) {
        float4 v = *reinterpret_cast<const float4*>(&s_ip[k0 * SD + j * 4]);
        buf[4 * j + 0] = v.x; buf[4 * j + 1] = v.y;
        buf[4 * j + 2] = v.z; buf[4 * j + 3] = v.w;
        float4 u = *reinterpret_cast<const float4*>(&s_iip[k0 * SD + j * 4]);
        ibuf[4 * j + 0] = u.x; ibuf[4 * j + 1] = u.y;
        ibuf[4 * j + 2] = u.z; ibuf[4 * j + 3] = u.w;
      }
      ushort8 o;
#pragma unroll
      for (int i = 0; i < 8; ++i) {
        float d1 = 0.f, d0 = 0.f;
#pragma unroll
        for (int d = 0; d < SD; ++d) {
          float a = buf[i * SD + d] - op[d];
          float b = ibuf[i * SD + d] - iop[d];
          d1 += a * a;
          d0 += b * b;
        }
        o[i] = bf16_bits(sqrtf(d1) - sqrtf(d0));
      }
      *reinterpret_cast<ushort8*>(Wt + (size_t)n * NUM_IN + k0) = o;
    }
  }
}

// ---------- GEMM: r7/r14 structure + front-loaded stages + hidden drain ----
// dbuf BK=64, 1 barrier per K-tile, counted-lgkm read lookahead (unchanged,
// measured 128.6us/47.5%). Changes: all 8 stage ops issued at tile START
// (drain age ~2000 cyc instead of ~300), and vmcnt(0) moved BEFORE the last
// MFMA cluster so the cluster covers any residual drain latency.
// 128B rows, chunk c stored at c^(row&7) (measured-zero swizzle).
__global__ __launch_bounds__(512, 1) void gemm_kernel(
    const ushort_t* __restrict__ A,    // [M][K] bf16
    const ushort_t* __restrict__ Bt,   // [N][K] bf16
    const float* __restrict__ bias,    // [N]
    float* __restrict__ C) {           // [M][N] f32
  __shared__ __align__(16) ushort_t sA[2 * TILEE];   // 64 KiB
  __shared__ __align__(16) ushort_t sB[2 * TILEE];   // 64 KiB

  const int tid  = threadIdx.x;
  const int w    = tid >> 6;         // 0..7
  const int l    = tid & 63;
  const int wm   = w >> 2;           // 0..1
  const int wn   = w & 3;            // 0..3
  const int lrow = l & 15;
  const int lkc  = l >> 4;           // 0..3

  // bijective XCD swizzle (512 = 8*64)
  const int orig = blockIdx.x;
  const int lin  = (orig & 7) * 64 + (orig >> 3);
  const int bx   = lin >> 4;         // 0..31 N-block
  const int by   = lin & 15;         // 0..15 M-block
  const int m0   = by * BM;
  const int n0   = bx * BN;

  // fragment read constants (elements)
  const int ck0 = (lkc ^ (lrow & 7)) * 8;         // k-half 0
  const int ck1 = ((4 + lkc) ^ (lrow & 7)) * 8;   // k-half 1
  const int Ab  = wm * 4096 + lrow * 64;
  const int Bb  = wn * 2048 + lrow * 64;

  // staging geometry (verified zero-conflict)
  const int d0 = tid, d1 = tid + 512;
  const int lr0 = d0 >> 3, lr1 = d1 >> 3;
  const int c0 = (d0 & 7) ^ (lr0 & 7);
  const int c1 = (d1 & 7) ^ (lr1 & 7);
  const ushort_t* pA0 = A  + (size_t)(m0 + (lr0 >> 6) * 128 + (lr0 & 63)) * NUM_IN + c0 * 8;
  const ushort_t* pA1 = A  + (size_t)(m0 + (lr1 >> 6) * 128 + (lr1 & 63)) * NUM_IN + c1 * 8;
  const ushort_t* pB0 = Bt + (size_t)(n0 + (lr0 >> 5) * 64 + (lr0 & 31)) * NUM_IN + c0 * 8;
  const ushort_t* pB1 = Bt + (size_t)(n0 + (lr1 >> 5) * 64 + (lr1 & 31)) * NUM_IN + c1 * 8;

#define GLDS(src, dst)                                                         \
  __builtin_amdgcn_global_load_lds(                                            \
      reinterpret_cast<const __attribute__((address_space(1))) uint32_t*>(     \
          (uintptr_t)(src)),                                                   \
      reinterpret_cast<__attribute__((address_space(3))) uint32_t*>(           \
          (uintptr_t)(dst)),                                                   \
      16, 0, 0)

#define STAGE_A(bs, mh, kt)                                                    \
  {                                                                            \
    GLDS(pA0 + (size_t)(mh) * 64 * NUM_IN + (kt),                              \
         &sA[(bs) * TILEE + (mh) * 8192 + tid * 8]);                           \
    GLDS(pA1 + (size_t)(mh) * 64 * NUM_IN + (kt),                              \
         &sA[(bs) * TILEE + (mh) * 8192 + tid * 8 + 4096]);                    \
  }
#define STAGE_B(bs, nh, kt)                                                    \
  {                                                                            \
    GLDS(pB0 + (size_t)(nh) * 32 * NUM_IN + (kt),                              \
         &sB[(bs) * TILEE + (nh) * 8192 + tid * 8]);                           \
    GLDS(pB1 + (size_t)(nh) * 32 * NUM_IN + (kt),                              \
         &sB[(bs) * TILEE + (nh) * 8192 + tid * 8 + 4096]);                    \
  }

// 4 ds_read_b128: one A-half, one k-half
#define RD_A(arr, bs, mh, ck)                                                  \
  {                                                                            \
    _Pragma("unroll")                                                          \
    for (int mi = 0; mi < 4; ++mi)                                             \
      arr[mi] = *reinterpret_cast<const bf16x8*>(                              \
          &sA[(bs) * TILEE + (mh) * 8192 + Ab + mi * 1024 + (ck)]);            \
  }
// 2 ds_read_b128: one B-half, one k-half
#define RD_B(arr, bs, nh, ck)                                                  \
  {                                                                            \
    _Pragma("unroll")                                                          \
    for (int nj = 0; nj < 2; ++nj)                                             \
      arr[nj] = *reinterpret_cast<const bf16x8*>(                              \
          &sB[(bs) * TILEE + (nh) * 8192 + Bb + nj * 1024 + (ck)]);            \
  }

// 8 MFMA: one C-quadrant x one k-half
#define MFMA8(mh, nh, Aa, Bb_)                                                 \
  {                                                                            \
    __builtin_amdgcn_s_setprio(1);                                             \
    _Pragma("unroll")                                                          \
    for (int mi = 0; mi < 4; ++mi)                                             \
      _Pragma("unroll")                                                        \
      for (int nj = 0; nj < 2; ++nj)                                           \
        acc[(mh) * 4 + mi][(nh) * 2 + nj] =                                    \
            __builtin_amdgcn_mfma_f32_16x16x32_bf16(                           \
                Aa[mi], Bb_[nj], acc[(mh) * 4 + mi][(nh) * 2 + nj], 0, 0, 0);  \
    __builtin_amdgcn_s_setprio(0);                                             \
  }

#define LGKM(n)  asm volatile("s_waitcnt lgkmcnt(" #n ")" ::: "memory")
#define SCHED0   __builtin_amdgcn_sched_barrier(0)
#define BARRIER  __builtin_amdgcn_s_barrier()
#define VMCNT0   asm volatile("s_waitcnt vmcnt(0)" ::: "memory")

// One K-tile. Stages front-loaded (max drain age); vmcnt(0) placed before
// the final MFMA cluster (cluster covers residual latency); barrier after.
#define KTILE(CUR, NXT, ktn)                                                   \
  {                                                                            \
    STAGE_A(NXT, 0, ktn) STAGE_B(NXT, 0, ktn)                                  \
    STAGE_A(NXT, 1, ktn) STAGE_B(NXT, 1, ktn)                                  \
    RD_A(aE, CUR, 0, ck0) RD_B(b0, CUR, 0, ck0)                                \
    RD_B(b1, CUR, 1, ck0)                    /* lookahead R1 */                \
    LGKM(2); SCHED0;                                                           \
    MFMA8(0, 0, aE, b0)                                                        \
    RD_A(aO, CUR, 1, ck0)                    /* lookahead R2 */                \
    LGKM(4); SCHED0;                                                           \
    MFMA8(0, 1, aE, b1)                                                        \
    LGKM(0); SCHED0;                                                           \
    MFMA8(1, 0, aO, b0)                                                        \
    RD_A(aE, CUR, 0, ck1) RD_B(b0, CUR, 0, ck1)  /* lookahead R4 */            \
    MFMA8(1, 1, aO, b1)                                                        \
    RD_B(b1, CUR, 1, ck1)                    /* lookahead R5 */                \
    LGKM(2); SCHED0;                                                           \
    MFMA8(0, 0, aE, b0)                                                        \
    RD_A(aO, CUR, 1, ck1)                    /* lookahead R6 */                \
    LGKM(4); SCHED0;                                                           \
    MFMA8(0, 1, aE, b1)                                                        \
    LGKM(0); SCHED0;                                                           \
    MFMA8(1, 0, aO, b0)                                                        \
    VMCNT0;                                  /* drain hidden under M11 */      \
    MFMA8(1, 1, aO, b1)                                                        \
    BARRIER;                                                                   \
  }

  f32x4 acc[8][4];
#pragma unroll
  for (int i = 0; i < 8; ++i)
#pragma unroll
    for (int j = 0; j < 4; ++j) acc[i][j] = f32x4{0.f, 0.f, 0.f, 0.f};

  bf16x8 aE[4], aO[4], b0[2], b1[2];

  // prologue: stage tile 0 into buf0
  STAGE_A(0, 0, 0) STAGE_B(0, 0, 0) STAGE_A(0, 1, 0) STAGE_B(0, 1, 0)
  VMCNT0;
  BARRIER;

#pragma unroll 1
  for (int tt = 0; tt < NT; tt += 2) {
    const int k1 = (tt + 1) * BK;                          // always < NUM_IN
    const int k2 = (tt + 2 < NT ? tt + 2 : NT - 1) * BK;   // clamped tail
    KTILE(0, 1, k1)
    KTILE(1, 0, k2)
  }

  // ---- epilogue: C = acc + bias ----
  const int er = l >> 4;          // 0..3
  const int ec = l & 15;
#pragma unroll
  for (int nh = 0; nh < 2; ++nh) {
#pragma unroll
    for (int nj = 0; nj < 2; ++nj) {
      const int col = n0 + wn * 64 + nh * 32 + nj * 16 + ec;
      const float bi = bias[col];
#pragma unroll
      for (int mh = 0; mh < 2; ++mh) {
#pragma unroll
        for (int mi = 0; mi < 4; ++mi) {
#pragma unroll
          for (int j = 0; j < 4; ++j) {
            const int row = m0 + wm * 128 + mh * 64 + mi * 16 + er * 4 + j;
            C[(size_t)row * NUM_OUT + col] =
                acc[mh * 4 + mi][nh * 2 + nj][j] + bi;
          }
        }
      }
    }
  }
#undef KTILE
#undef STAGE_A
#undef STAGE_B
#undef RD_A
#undef RD_B
#undef MFMA8
#undef GLDS
}

extern "C" void kernel_launch(void* const* d_in, const int* in_sizes, int n_in,
                              void* d_out, int out_size, void* d_ws, size_t ws_size,
                              hipStream_t stream) {
  const float* inputs   = (const float*)d_in[0];  // [4096,2048]
  const float* init_in  = (const float*)d_in[1];  // [2048,1,5]
  const float* init_out = (const float*)d_in[2];  // [1,8192,5]
  const float* in_pos   = (const float*)d_in[3];  // [2048,1,5]
  const float* out_pos  = (const float*)d_in[4];  // [1,8192,5]
  const float* biases   = (const float*)d_in[5];  // [8192]
  float* out = (float*)d_out;                     // [4096,8192]

  ushort_t* Abf = (ushort_t*)d_ws;
  ushort_t* Wt  = (ushort_t*)((char*)d_ws + (size_t)BATCH * NUM_IN * 2);

  aux_kernel<<<512, 256, 0, stream>>>(inputs, Abf,
                                      in_pos, out_pos, init_in, init_out, Wt);
  gemm_kernel<<<(BATCH / BM) * (NUM_OUT / BN), 512, 0, stream>>>(
      Abf, Wt, biases, out);
}

// Round 17
// 155.790 us; speedup vs baseline: 1.1038x; 1.0269x over previous
//
#include <hip/hip_runtime.h>
#include <hip/hip_bf16.h>
#include <stdint.h>

#define NUM_IN  2048   // K
#define NUM_OUT 8192   // N
#define BATCH   4096   // M
#define SD      5

#define BM 256
#define BN 256
#define BK 64
#define NT (NUM_IN / BK)      // 32 K-tiles
#define TILEE (BM * BK)       // 16384 elements per operand per K-tile

typedef __bf16 bf16x8 __attribute__((ext_vector_type(8)));
typedef float  f32x4  __attribute__((ext_vector_type(4)));
typedef unsigned short ushort_t;
typedef ushort_t ushort8 __attribute__((ext_vector_type(8)));

static __device__ __forceinline__ ushort_t bf16_bits(float f) {
  __hip_bfloat16 h = __float2bfloat16(f);
  ushort_t u;
  __builtin_memcpy(&u, &h, 2);
  return u;
}

// ---------- fused aux: blocks [0,256) genw (32 n each), [256,512) cvt ----------
__global__ __launch_bounds__(256) void aux_kernel(
    const float* __restrict__ inputs,   // [BATCH][NUM_IN] f32
    ushort_t* __restrict__ Abf,         // [BATCH][NUM_IN] bf16
    const float* __restrict__ in_pos, const float* __restrict__ out_pos,
    const float* __restrict__ init_in, const float* __restrict__ init_out,
    ushort_t* __restrict__ Wt) {        // [NUM_OUT][NUM_IN] bf16
  __shared__ float s_ip[NUM_IN * SD];    // 40 KB
  __shared__ float s_iip[NUM_IN * SD];   // 40 KB
  const int tid = threadIdx.x;

  if (blockIdx.x >= 256) {
    // ---- cvt path: 32768 elems ----
    const size_t base = (size_t)(blockIdx.x - 256) * 32768;
#pragma unroll
    for (int c = 0; c < 16; ++c) {
      const size_t i = base + (size_t)c * 2048 + tid * 8;
      float4 v0 = *reinterpret_cast<const float4*>(inputs + i);
      float4 v1 = *reinterpret_cast<const float4*>(inputs + i + 4);
      ushort8 o;
      o[0] = bf16_bits(v0.x); o[1] = bf16_bits(v0.y);
      o[2] = bf16_bits(v0.z); o[3] = bf16_bits(v0.w);
      o[4] = bf16_bits(v1.x); o[5] = bf16_bits(v1.y);
      o[6] = bf16_bits(v1.z); o[7] = bf16_bits(v1.w);
      *reinterpret_cast<ushort8*>(Abf + i) = o;
    }
    return;
  }

  // ---- genw path: 32 n per block (stages 80KB pos tables once per 32 n) ----
#pragma unroll
  for (int i = 0; i < 10; ++i) {
    const int idx = i * 1024 + tid * 4;
    *reinterpret_cast<float4*>(&s_ip[idx]) =
        *reinterpret_cast<const float4*>(in_pos + idx);
    *reinterpret_cast<float4*>(&s_iip[idx]) =
        *reinterpret_cast<const float4*>(init_in + idx);
  }
  __syncthreads();

#pragma unroll 1
  for (int half = 0; half < 2; ++half) {
    const int n  = blockIdx.x * 32 + half * 16 + (tid >> 4);
    const int kg = tid & 15;
    float op[SD], iop[SD];
#pragma unroll
    for (int d = 0; d < SD; ++d) {
      op[d]  = out_pos[n * SD + d];
      iop[d] = init_out[n * SD + d];
    }
#pragma unroll 1
    for (int kb = 0; kb < 16; ++kb) {
      const int k0 = kb * 128 + kg * 8;
      float buf[40], ibuf[40];
#pragma unroll
      for (int j = 0; j < 10; ++j) {
        float4 v = *reinterpret_cast<const float4*>(&s_ip[k0 * SD + j * 4]);
        buf[4 * j + 0] = v.x; buf[4 * j + 1] = v.y;
        buf[4 * j + 2] = v.z; buf[4 * j + 3] = v.w;
        float4 u = *reinterpret_cast<const float4*>(&s_iip[k0 * SD + j * 4]);
        ibuf[4 * j + 0] = u.x; ibuf[4 * j + 1] = u.y;
        ibuf[4 * j + 2] = u.z; ibuf[4 * j + 3] = u.w;
      }
      ushort8 o;
#pragma unroll
      for (int i = 0; i < 8; ++i) {
        float d1 = 0.f, d0 = 0.f;
#pragma unroll
        for (int d = 0; d < SD; ++d) {
          float a = buf[i * SD + d] - op[d];
          float b = ibuf[i * SD + d] - iop[d];
          d1 += a * a;
          d0 += b * b;
        }
        o[i] = bf16_bits(sqrtf(d1) - sqrtf(d0));
      }
      *reinterpret_cast<ushort8*>(Wt + (size_t)n * NUM_IN + k0) = o;
    }
  }
}

// ---------- GEMM: r7/r14 structure (best measured: 128.6us, 47.5%) ----------
// Single change vs r14: s_setprio removed from MFMA clusters (m190 A/B:
// setprio HURTS barrier-synced GEMM; T5 needs an 8-phase role-split).
// dbuf BK=64, 1 barrier + vmcnt(0) per K-tile, counted-lgkm read lookahead.
// 128B rows, chunk c stored at c^(row&7) (measured-zero swizzle).
__global__ __launch_bounds__(512, 1) void gemm_kernel(
    const ushort_t* __restrict__ A,    // [M][K] bf16
    const ushort_t* __restrict__ Bt,   // [N][K] bf16
    const float* __restrict__ bias,    // [N]
    float* __restrict__ C) {           // [M][N] f32
  __shared__ __align__(16) ushort_t sA[2 * TILEE];   // 64 KiB
  __shared__ __align__(16) ushort_t sB[2 * TILEE];   // 64 KiB

  const int tid  = threadIdx.x;
  const int w    = tid >> 6;         // 0..7
  const int l    = tid & 63;
  const int wm   = w >> 2;           // 0..1
  const int wn   = w & 3;            // 0..3
  const int lrow = l & 15;
  const int lkc  = l >> 4;           // 0..3

  // bijective XCD swizzle (512 = 8*64)
  const int orig = blockIdx.x;
  const int lin  = (orig & 7) * 64 + (orig >> 3);
  const int bx   = lin >> 4;         // 0..31 N-block
  const int by   = lin & 15;         // 0..15 M-block
  const int m0   = by * BM;
  const int n0   = bx * BN;

  // fragment read constants (elements)
  const int ck0 = (lkc ^ (lrow & 7)) * 8;         // k-half 0
  const int ck1 = ((4 + lkc) ^ (lrow & 7)) * 8;   // k-half 1
  const int Ab  = wm * 4096 + lrow * 64;
  const int Bb  = wn * 2048 + lrow * 64;

  // staging geometry (verified zero-conflict)
  const int d0 = tid, d1 = tid + 512;
  const int lr0 = d0 >> 3, lr1 = d1 >> 3;
  const int c0 = (d0 & 7) ^ (lr0 & 7);
  const int c1 = (d1 & 7) ^ (lr1 & 7);
  const ushort_t* pA0 = A  + (size_t)(m0 + (lr0 >> 6) * 128 + (lr0 & 63)) * NUM_IN + c0 * 8;
  const ushort_t* pA1 = A  + (size_t)(m0 + (lr1 >> 6) * 128 + (lr1 & 63)) * NUM_IN + c1 * 8;
  const ushort_t* pB0 = Bt + (size_t)(n0 + (lr0 >> 5) * 64 + (lr0 & 31)) * NUM_IN + c0 * 8;
  const ushort_t* pB1 = Bt + (size_t)(n0 + (lr1 >> 5) * 64 + (lr1 & 31)) * NUM_IN + c1 * 8;

#define GLDS(src, dst)                                                         \
  __builtin_amdgcn_global_load_lds(                                            \
      reinterpret_cast<const __attribute__((address_space(1))) uint32_t*>(     \
          (uintptr_t)(src)),                                                   \
      reinterpret_cast<__attribute__((address_space(3))) uint32_t*>(           \
          (uintptr_t)(dst)),                                                   \
      16, 0, 0)

#define STAGE_A(bs, mh, kt)                                                    \
  {                                                                            \
    GLDS(pA0 + (size_t)(mh) * 64 * NUM_IN + (kt),                              \
         &sA[(bs) * TILEE + (mh) * 8192 + tid * 8]);                           \
    GLDS(pA1 + (size_t)(mh) * 64 * NUM_IN + (kt),                              \
         &sA[(bs) * TILEE + (mh) * 8192 + tid * 8 + 4096]);                    \
  }
#define STAGE_B(bs, nh, kt)                                                    \
  {                                                                            \
    GLDS(pB0 + (size_t)(nh) * 32 * NUM_IN + (kt),                              \
         &sB[(bs) * TILEE + (nh) * 8192 + tid * 8]);                           \
    GLDS(pB1 + (size_t)(nh) * 32 * NUM_IN + (kt),                              \
         &sB[(bs) * TILEE + (nh) * 8192 + tid * 8 + 4096]);                    \
  }

// 4 ds_read_b128: one A-half, one k-half
#define RD_A(arr, bs, mh, ck)                                                  \
  {                                                                            \
    _Pragma("unroll")                                                          \
    for (int mi = 0; mi < 4; ++mi)                                             \
      arr[mi] = *reinterpret_cast<const bf16x8*>(                              \
          &sA[(bs) * TILEE + (mh) * 8192 + Ab + mi * 1024 + (ck)]);            \
  }
// 2 ds_read_b128: one B-half, one k-half
#define RD_B(arr, bs, nh, ck)                                                  \
  {                                                                            \
    _Pragma("unroll")                                                          \
    for (int nj = 0; nj < 2; ++nj)                                             \
      arr[nj] = *reinterpret_cast<const bf16x8*>(                              \
          &sB[(bs) * TILEE + (nh) * 8192 + Bb + nj * 1024 + (ck)]);            \
  }

// 8 MFMA: one C-quadrant x one k-half (no setprio — m190)
#define MFMA8(mh, nh, Aa, Bb_)                                                 \
  {                                                                            \
    _Pragma("unroll")                                                          \
    for (int mi = 0; mi < 4; ++mi)                                             \
      _Pragma("unroll")                                                        \
      for (int nj = 0; nj < 2; ++nj)                                           \
        acc[(mh) * 4 + mi][(nh) * 2 + nj] =                                    \
            __builtin_amdgcn_mfma_f32_16x16x32_bf16(                           \
                Aa[mi], Bb_[nj], acc[(mh) * 4 + mi][(nh) * 2 + nj], 0, 0, 0);  \
  }

#define LGKM(n)  asm volatile("s_waitcnt lgkmcnt(" #n ")" ::: "memory")
#define SCHED0   __builtin_amdgcn_sched_barrier(0)
#define BARRIER  __builtin_amdgcn_s_barrier()
#define VMCNT0   asm volatile("s_waitcnt vmcnt(0)" ::: "memory")

#define KTILE(CUR, NXT, ktn)                                                   \
  {                                                                            \
    STAGE_A(NXT, 0, ktn)                                                       \
    RD_A(aE, CUR, 0, ck0) RD_B(b0, CUR, 0, ck0)                                \
    RD_B(b1, CUR, 1, ck0)                    /* lookahead R1 */                \
    LGKM(2); SCHED0;                                                           \
    MFMA8(0, 0, aE, b0)                                                        \
    STAGE_B(NXT, 0, ktn)                                                       \
    RD_A(aO, CUR, 1, ck0)                    /* lookahead R2 */                \
    LGKM(4); SCHED0;                                                           \
    MFMA8(0, 1, aE, b1)                                                        \
    STAGE_A(NXT, 1, ktn)                                                       \
    LGKM(0); SCHED0;                                                           \
    MFMA8(1, 0, aO, b0)                                                        \
    STAGE_B(NXT, 1, ktn)                                                       \
    RD_A(aE, CUR, 0, ck1) RD_B(b0, CUR, 0, ck1)  /* lookahead R4 */            \
    MFMA8(1, 1, aO, b1)                                                        \
    RD_B(b1, CUR, 1, ck1)                    /* lookahead R5 */                \
    LGKM(2); SCHED0;                                                           \
    MFMA8(0, 0, aE, b0)                                                        \
    RD_A(aO, CUR, 1, ck1)                    /* lookahead R6 */                \
    LGKM(4); SCHED0;                                                           \
    MFMA8(0, 1, aE, b1)                                                        \
    LGKM(0); SCHED0;                                                           \
    MFMA8(1, 0, aO, b0)                                                        \
    MFMA8(1, 1, aO, b1)                                                        \
    VMCNT0;                                                                    \
    BARRIER;                                                                   \
  }

  f32x4 acc[8][4];
#pragma unroll
  for (int i = 0; i < 8; ++i)
#pragma unroll
    for (int j = 0; j < 4; ++j) acc[i][j] = f32x4{0.f, 0.f, 0.f, 0.f};

  bf16x8 aE[4], aO[4], b0[2], b1[2];

  // prologue: stage tile 0 into buf0
  STAGE_A(0, 0, 0) STAGE_B(0, 0, 0) STAGE_A(0, 1, 0) STAGE_B(0, 1, 0)
  VMCNT0;
  BARRIER;

#pragma unroll 1
  for (int tt = 0; tt < NT; tt += 2) {
    const int k1 = (tt + 1) * BK;                          // always < NUM_IN
    const int k2 = (tt + 2 < NT ? tt + 2 : NT - 1) * BK;   // clamped tail
    KTILE(0, 1, k1)
    KTILE(1, 0, k2)
  }

  // ---- epilogue: C = acc + bias ----
  const int er = l >> 4;          // 0..3
  const int ec = l & 15;
#pragma unroll
  for (int nh = 0; nh < 2; ++nh) {
#pragma unroll
    for (int nj = 0; nj < 2; ++nj) {
      const int col = n0 + wn * 64 + nh * 32 + nj * 16 + ec;
      const float bi = bias[col];
#pragma unroll
      for (int mh = 0; mh < 2; ++mh) {
#pragma unroll
        for (int mi = 0; mi < 4; ++mi) {
#pragma unroll
          for (int j = 0; j < 4; ++j) {
            const int row = m0 + wm * 128 + mh * 64 + mi * 16 + er * 4 + j;
            C[(size_t)row * NUM_OUT + col] =
                acc[mh * 4 + mi][nh * 2 + nj][j] + bi;
          }
        }
      }
    }
  }
#undef KTILE
#undef STAGE_A
#undef STAGE_B
#undef RD_A
#undef RD_B
#undef MFMA8
#undef GLDS
}

extern "C" void kernel_launch(void* const* d_in, const int* in_sizes, int n_in,
                              void* d_out, int out_size, void* d_ws, size_t ws_size,
                              hipStream_t stream) {
  const float* inputs   = (const float*)d_in[0];  // [4096,2048]
  const float* init_in  = (const float*)d_in[1];  // [2048,1,5]
  const float* init_out = (const float*)d_in[2];  // [1,8192,5]
  const float* in_pos   = (const float*)d_in[3];  // [2048,1,5]
  const float* out_pos  = (const float*)d_in[4];  // [1,8192,5]
  const float* biases   = (const float*)d_in[5];  // [8192]
  float* out = (float*)d_out;                     // [4096,8192]

  ushort_t* Abf = (ushort_t*)d_ws;
  ushort_t* Wt  = (ushort_t*)((char*)d_ws + (size_t)BATCH * NUM_IN * 2);

  aux_kernel<<<512, 256, 0, stream>>>(inputs, Abf,
                                      in_pos, out_pos, init_in, init_out, Wt);
  gemm_kernel<<<(BATCH / BM) * (NUM_OUT / BN), 512, 0, stream>>>(
      Abf, Wt, biases, out);
}

// Round 18
// 152.802 us; speedup vs baseline: 1.1254x; 1.0196x over previous
//
#include <hip/hip_runtime.h>
#include <hip/hip_bf16.h>
#include <stdint.h>

#define NUM_IN  2048   // K
#define NUM_OUT 8192   // N
#define BATCH   4096   // M
#define SD      5

#define BM 256
#define BN 256
#define BK 64
#define NT (NUM_IN / BK)      // 32 K-tiles
#define TILEE (BM * BK)       // 16384 elements per operand per K-tile

typedef __bf16 bf16x8 __attribute__((ext_vector_type(8)));
typedef float  f32x4  __attribute__((ext_vector_type(4)));
typedef unsigned short ushort_t;
typedef ushort_t ushort8 __attribute__((ext_vector_type(8)));

static __device__ __forceinline__ ushort_t bf16_bits(float f) {
  __hip_bfloat16 h = __float2bfloat16(f);
  ushort_t u;
  __builtin_memcpy(&u, &h, 2);
  return u;
}

// ---------- fused aux: blocks [0,512) genw, [512,1024) cvt ----------
// genw: 16 n per block, in_pos/init_in staged in LDS (80 KB).
// cvt: 16384 f32->bf16 per block, fully coalesced.
// Independent workloads run CONCURRENTLY across CUs (one launch).
__global__ __launch_bounds__(256) void aux_kernel(
    const float* __restrict__ inputs,   // [BATCH][NUM_IN] f32
    ushort_t* __restrict__ Abf,         // [BATCH][NUM_IN] bf16
    const float* __restrict__ in_pos, const float* __restrict__ out_pos,
    const float* __restrict__ init_in, const float* __restrict__ init_out,
    ushort_t* __restrict__ Wt) {        // [NUM_OUT][NUM_IN] bf16
  __shared__ float s_ip[NUM_IN * SD];    // 40 KB
  __shared__ float s_iip[NUM_IN * SD];   // 40 KB
  const int tid = threadIdx.x;

  if (blockIdx.x >= 512) {
    // ---- cvt path ----
    const size_t base = (size_t)(blockIdx.x - 512) * 16384;
#pragma unroll
    for (int c = 0; c < 8; ++c) {
      const size_t i = base + (size_t)c * 2048 + tid * 8;
      float4 v0 = *reinterpret_cast<const float4*>(inputs + i);
      float4 v1 = *reinterpret_cast<const float4*>(inputs + i + 4);
      ushort8 o;
      o[0] = bf16_bits(v0.x); o[1] = bf16_bits(v0.y);
      o[2] = bf16_bits(v0.z); o[3] = bf16_bits(v0.w);
      o[4] = bf16_bits(v1.x); o[5] = bf16_bits(v1.y);
      o[6] = bf16_bits(v1.z); o[7] = bf16_bits(v1.w);
      *reinterpret_cast<ushort8*>(Abf + i) = o;
    }
    return;
  }

  // ---- genw path ----
#pragma unroll
  for (int i = 0; i < 10; ++i) {
    const int idx = i * 1024 + tid * 4;
    *reinterpret_cast<float4*>(&s_ip[idx]) =
        *reinterpret_cast<const float4*>(in_pos + idx);
    *reinterpret_cast<float4*>(&s_iip[idx]) =
        *reinterpret_cast<const float4*>(init_in + idx);
  }
  __syncthreads();

  const int n  = blockIdx.x * 16 + (tid >> 4);
  const int kg = tid & 15;
  float op[SD], iop[SD];
#pragma unroll
  for (int d = 0; d < SD; ++d) {
    op[d]  = out_pos[n * SD + d];
    iop[d] = init_out[n * SD + d];
  }
#pragma unroll 1
  for (int kb = 0; kb < 16; ++kb) {
    const int k0 = kb * 128 + kg * 8;
    float buf[40], ibuf[40];
#pragma unroll
    for (int j = 0; j < 10; ++j) {
      float4 v = *reinterpret_cast<const float4*>(&s_ip[k0 * SD + j * 4]);
      buf[4 * j + 0] = v.x; buf[4 * j + 1] = v.y;
      buf[4 * j + 2] = v.z; buf[4 * j + 3] = v.w;
      float4 u = *reinterpret_cast<const float4*>(&s_iip[k0 * SD + j * 4]);
      ibuf[4 * j + 0] = u.x; ibuf[4 * j + 1] = u.y;
      ibuf[4 * j + 2] = u.z; ibuf[4 * j + 3] = u.w;
    }
    ushort8 o;
#pragma unroll
    for (int i = 0; i < 8; ++i) {
      float d1 = 0.f, d0 = 0.f;
#pragma unroll
      for (int d = 0; d < SD; ++d) {
        float a = buf[i * SD + d] - op[d];
        float b = ibuf[i * SD + d] - iop[d];
        d1 += a * a;
        d0 += b * b;
      }
      o[i] = bf16_bits(sqrtf(d1) - sqrtf(d0));
    }
    *reinterpret_cast<ushort8*>(Wt + (size_t)n * NUM_IN + k0) = o;
  }
}

// ---------- GEMM: round-7/14 kernel verbatim (best measured: 128.6us, 47.5%) --
// de-lockstepped 256^2, 1 barrier per K-tile, dbuf BK=64, counted-lgkm
// read lookahead. 128B rows, chunk c stored at c^(row&7) (measured-zero).
__global__ __launch_bounds__(512, 1) void gemm_kernel(
    const ushort_t* __restrict__ A,    // [M][K] bf16
    const ushort_t* __restrict__ Bt,   // [N][K] bf16
    const float* __restrict__ bias,    // [N]
    float* __restrict__ C) {           // [M][N] f32
  __shared__ __align__(16) ushort_t sA[2 * TILEE];   // 64 KiB
  __shared__ __align__(16) ushort_t sB[2 * TILEE];   // 64 KiB

  const int tid  = threadIdx.x;
  const int w    = tid >> 6;         // 0..7
  const int l    = tid & 63;
  const int wm   = w >> 2;           // 0..1
  const int wn   = w & 3;            // 0..3
  const int lrow = l & 15;
  const int lkc  = l >> 4;           // 0..3

  // bijective XCD swizzle (512 = 8*64)
  const int orig = blockIdx.x;
  const int lin  = (orig & 7) * 64 + (orig >> 3);
  const int bx   = lin >> 4;         // 0..31 N-block
  const int by   = lin & 15;         // 0..15 M-block
  const int m0   = by * BM;
  const int n0   = bx * BN;

  // fragment read constants (elements)
  const int ck0 = (lkc ^ (lrow & 7)) * 8;         // k-half 0
  const int ck1 = ((4 + lkc) ^ (lrow & 7)) * 8;   // k-half 1
  const int Ab  = wm * 4096 + lrow * 64;
  const int Bb  = wn * 2048 + lrow * 64;

  // staging geometry (verified zero-conflict)
  const int d0 = tid, d1 = tid + 512;
  const int lr0 = d0 >> 3, lr1 = d1 >> 3;
  const int c0 = (d0 & 7) ^ (lr0 & 7);
  const int c1 = (d1 & 7) ^ (lr1 & 7);
  const ushort_t* pA0 = A  + (size_t)(m0 + (lr0 >> 6) * 128 + (lr0 & 63)) * NUM_IN + c0 * 8;
  const ushort_t* pA1 = A  + (size_t)(m0 + (lr1 >> 6) * 128 + (lr1 & 63)) * NUM_IN + c1 * 8;
  const ushort_t* pB0 = Bt + (size_t)(n0 + (lr0 >> 5) * 64 + (lr0 & 31)) * NUM_IN + c0 * 8;
  const ushort_t* pB1 = Bt + (size_t)(n0 + (lr1 >> 5) * 64 + (lr1 & 31)) * NUM_IN + c1 * 8;

#define GLDS(src, dst)                                                         \
  __builtin_amdgcn_global_load_lds(                                            \
      reinterpret_cast<const __attribute__((address_space(1))) uint32_t*>(     \
          (uintptr_t)(src)),                                                   \
      reinterpret_cast<__attribute__((address_space(3))) uint32_t*>(           \
          (uintptr_t)(dst)),                                                   \
      16, 0, 0)

#define STAGE_A(bs, mh, kt)                                                    \
  {                                                                            \
    GLDS(pA0 + (size_t)(mh) * 64 * NUM_IN + (kt),                              \
         &sA[(bs) * TILEE + (mh) * 8192 + tid * 8]);                           \
    GLDS(pA1 + (size_t)(mh) * 64 * NUM_IN + (kt),                              \
         &sA[(bs) * TILEE + (mh) * 8192 + tid * 8 + 4096]);                    \
  }
#define STAGE_B(bs, nh, kt)                                                    \
  {                                                                            \
    GLDS(pB0 + (size_t)(nh) * 32 * NUM_IN + (kt),                              \
         &sB[(bs) * TILEE + (nh) * 8192 + tid * 8]);                           \
    GLDS(pB1 + (size_t)(nh) * 32 * NUM_IN + (kt),                              \
         &sB[(bs) * TILEE + (nh) * 8192 + tid * 8 + 4096]);                    \
  }

// 4 ds_read_b128: one A-half, one k-half
#define RD_A(arr, bs, mh, ck)                                                  \
  {                                                                            \
    _Pragma("unroll")                                                          \
    for (int mi = 0; mi < 4; ++mi)                                             \
      arr[mi] = *reinterpret_cast<const bf16x8*>(                              \
          &sA[(bs) * TILEE + (mh) * 8192 + Ab + mi * 1024 + (ck)]);            \
  }
// 2 ds_read_b128: one B-half, one k-half
#define RD_B(arr, bs, nh, ck)                                                  \
  {                                                                            \
    _Pragma("unroll")                                                          \
    for (int nj = 0; nj < 2; ++nj)                                             \
      arr[nj] = *reinterpret_cast<const bf16x8*>(                              \
          &sB[(bs) * TILEE + (nh) * 8192 + Bb + nj * 1024 + (ck)]);            \
  }

// 8 MFMA: one C-quadrant x one k-half
#define MFMA8(mh, nh, Aa, Bb_)                                                 \
  {                                                                            \
    __builtin_amdgcn_s_setprio(1);                                             \
    _Pragma("unroll")                                                          \
    for (int mi = 0; mi < 4; ++mi)                                             \
      _Pragma("unroll")                                                        \
      for (int nj = 0; nj < 2; ++nj)                                           \
        acc[(mh) * 4 + mi][(nh) * 2 + nj] =                                    \
            __builtin_amdgcn_mfma_f32_16x16x32_bf16(                           \
                Aa[mi], Bb_[nj], acc[(mh) * 4 + mi][(nh) * 2 + nj], 0, 0, 0);  \
    __builtin_amdgcn_s_setprio(0);                                             \
  }

#define LGKM(n)  asm volatile("s_waitcnt lgkmcnt(" #n ")" ::: "memory")
#define SCHED0   __builtin_amdgcn_sched_barrier(0)
#define BARRIER  __builtin_amdgcn_s_barrier()
#define VMCNT0   asm volatile("s_waitcnt vmcnt(0)" ::: "memory")

#define KTILE(CUR, NXT, ktn)                                                   \
  {                                                                            \
    STAGE_A(NXT, 0, ktn)                                                       \
    RD_A(aE, CUR, 0, ck0) RD_B(b0, CUR, 0, ck0)                                \
    RD_B(b1, CUR, 1, ck0)                    /* lookahead R1 */                \
    LGKM(2); SCHED0;                                                           \
    MFMA8(0, 0, aE, b0)                                                        \
    STAGE_B(NXT, 0, ktn)                                                       \
    RD_A(aO, CUR, 1, ck0)                    /* lookahead R2 */                \
    LGKM(4); SCHED0;                                                           \
    MFMA8(0, 1, aE, b1)                                                        \
    STAGE_A(NXT, 1, ktn)                                                       \
    LGKM(0); SCHED0;                                                           \
    MFMA8(1, 0, aO, b0)                                                        \
    STAGE_B(NXT, 1, ktn)                                                       \
    RD_A(aE, CUR, 0, ck1) RD_B(b0, CUR, 0, ck1)  /* lookahead R4 */            \
    MFMA8(1, 1, aO, b1)                                                        \
    RD_B(b1, CUR, 1, ck1)                    /* lookahead R5 */                \
    LGKM(2); SCHED0;                                                           \
    MFMA8(0, 0, aE, b0)                                                        \
    RD_A(aO, CUR, 1, ck1)                    /* lookahead R6 */                \
    LGKM(4); SCHED0;                                                           \
    MFMA8(0, 1, aE, b1)                                                        \
    LGKM(0); SCHED0;                                                           \
    MFMA8(1, 0, aO, b0)                                                        \
    MFMA8(1, 1, aO, b1)                                                        \
    VMCNT0;                                                                    \
    BARRIER;                                                                   \
  }

  f32x4 acc[8][4];
#pragma unroll
  for (int i = 0; i < 8; ++i)
#pragma unroll
    for (int j = 0; j < 4; ++j) acc[i][j] = f32x4{0.f, 0.f, 0.f, 0.f};

  bf16x8 aE[4], aO[4], b0[2], b1[2];

  // prologue: stage tile 0 into buf0
  STAGE_A(0, 0, 0) STAGE_B(0, 0, 0) STAGE_A(0, 1, 0) STAGE_B(0, 1, 0)
  VMCNT0;
  BARRIER;

#pragma unroll 1
  for (int tt = 0; tt < NT; tt += 2) {
    const int k1 = (tt + 1) * BK;                          // always < NUM_IN
    const int k2 = (tt + 2 < NT ? tt + 2 : NT - 1) * BK;   // clamped tail
    KTILE(0, 1, k1)
    KTILE(1, 0, k2)
  }

  // ---- epilogue: C = acc + bias ----
  const int er = l >> 4;          // 0..3
  const int ec = l & 15;
#pragma unroll
  for (int nh = 0; nh < 2; ++nh) {
#pragma unroll
    for (int nj = 0; nj < 2; ++nj) {
      const int col = n0 + wn * 64 + nh * 32 + nj * 16 + ec;
      const float bi = bias[col];
#pragma unroll
      for (int mh = 0; mh < 2; ++mh) {
#pragma unroll
        for (int mi = 0; mi < 4; ++mi) {
#pragma unroll
          for (int j = 0; j < 4; ++j) {
            const int row = m0 + wm * 128 + mh * 64 + mi * 16 + er * 4 + j;
            C[(size_t)row * NUM_OUT + col] =
                acc[mh * 4 + mi][nh * 2 + nj][j] + bi;
          }
        }
      }
    }
  }
#undef KTILE
#undef STAGE_A
#undef STAGE_B
#undef RD_A
#undef RD_B
#undef MFMA8
#undef GLDS
}

extern "C" void kernel_launch(void* const* d_in, const int* in_sizes, int n_in,
                              void* d_out, int out_size, void* d_ws, size_t ws_size,
                              hipStream_t stream) {
  const float* inputs   = (const float*)d_in[0];  // [4096,2048]
  const float* init_in  = (const float*)d_in[1];  // [2048,1,5]
  const float* init_out = (const float*)d_in[2];  // [1,8192,5]
  const float* in_pos   = (const float*)d_in[3];  // [2048,1,5]
  const float* out_pos  = (const float*)d_in[4];  // [1,8192,5]
  const float* biases   = (const float*)d_in[5];  // [8192]
  float* out = (float*)d_out;                     // [4096,8192]

  ushort_t* Abf = (ushort_t*)d_ws;
  ushort_t* Wt  = (ushort_t*)((char*)d_ws + (size_t)BATCH * NUM_IN * 2);

  aux_kernel<<<1024, 256, 0, stream>>>(inputs, Abf,
                                       in_pos, out_pos, init_in, init_out, Wt);
  gemm_kernel<<<(BATCH / BM) * (NUM_OUT / BN), 512, 0, stream>>>(
      Abf, Wt, biases, out);
}